// Round 6
// baseline (112.790 us; speedup 1.0000x reference)
//
#include <hip/hip_runtime.h>
#include <hip/hip_cooperative_groups.h>
#include <hip/hip_bf16.h>

namespace cg = cooperative_groups;

#define N 1024
#define D 128
#define LEAK 0.2f

#define MROWS 4          // i-rows per block in phase B
#define MJC 64           // j chunk
#define NCHUNK (N / MJC) // 16

// workspace layout (float offsets)
#define OFF_MT   0
#define OFF_W2T  16384
#define OFF_WPD  32768
#define OFF_WUT  32896
#define OFF_S1   33024
#define OFF_S2   34048
#define OFF_BASE 35072

// ---------------------------------------------------------------------------
// One cooperative kernel: 256 blocks x 512 threads, 1 block/CU.
//   A1: Mt / W2t / wpd,wut / s1,s2      (block-range split)
//   grid.sync()
//   A2: base rows 4b..4b+3              (all blocks)
//   grid.sync()
//   B : alpha (LDS) + masked-relu-weighted j-sum + W2t GEMM -> out
__global__ __launch_bounds__(512, 1) void fused_kernel(
    const float* __restrict__ h, const int* __restrict__ adj,
    const float* __restrict__ pd, const float* __restrict__ ut,
    const float* __restrict__ W, const float* __restrict__ a,
    const float* __restrict__ W1, const float* __restrict__ b1,
    const float* __restrict__ W2, const float* __restrict__ b2,
    float* __restrict__ Mt, float* __restrict__ W2t,
    float* __restrict__ wpd, float* __restrict__ wut,
    float* __restrict__ s1, float* __restrict__ s2,
    float* __restrict__ base, float* __restrict__ out) {

    __shared__ float pool[16512];          // 64.5KB  A1: 129-stride staging; B: bl[2][64][128]/racc[32][4][128]
    __shared__ float al[MROWS][N];         // 16KB alpha
    __shared__ float4 sc[2][MROWS][MJC];   // 8KB {pd, ut, alpha, 0}
    __shared__ float tl[MROWS][D];         // 2KB  A2: h stage; B: reduced t
    __shared__ float red[8], red2[8], gsum[MROWS];

    const int b = blockIdx.x, tid = threadIdx.x;
    cg::grid_group grid = cg::this_grid();

    // ========================= A1 =========================
    if (b < 32) {
        // Mt rows 4b..4b+3 : Mt[k][d] = sum_q W1[d][q] * W[q][k]
        #pragma unroll
        for (int p = 0; p < 32; p++) {
            int idx = tid + p * 512, row = idx >> 7, col = idx & 127;
            pool[row * 129 + col] = W1[row * (D + 2) + col];
        }
        __syncthreads();
        int d = tid & 127, kl = tid >> 7, k = 4 * b + kl;
        float acc = 0.f;
        #pragma unroll 8
        for (int q = 0; q < D; q++)
            acc = fmaf(pool[d * 129 + q], W[q * D + k], acc);
        Mt[k * D + d] = acc;
    } else if (b < 36) {
        // W2t 32-row tile
        int kbase = 32 * (b - 32);
        #pragma unroll
        for (int p = 0; p < 8; p++) {
            int idx = tid + p * 512, rd = idx >> 5, cc = idx & 31;
            pool[cc * 129 + rd] = W2[rd * D + kbase + cc];
        }
        __syncthreads();
        #pragma unroll
        for (int p = 0; p < 8; p++) {
            int idx = tid + p * 512, kl = idx >> 7, dd = idx & 127;
            W2t[(kbase + kl) * D + dd] = pool[kl * 129 + dd];
        }
    } else if (b == 36) {
        if (tid < 128) wpd[tid] = W1[tid * (D + 2) + D];
        else if (tid < 256) wut[tid - 128] = W1[(tid - 128) * (D + 2) + D + 1];
    } else if (b >= 128) {
        // s1/s2 for rows (b-128)*8 ..+7 ; va/vb recomputed locally (trivial)
        float* vab = pool;          // [2][128]
        float* hls = pool + 256;    // [8][128]
        int i0 = (b - 128) * 8;
        if (tid < 256) {
            int half = tid >> 7, k = tid & 127;
            const float* av = a + half * D;
            float acc = 0.f;
            #pragma unroll 8
            for (int q = 0; q < D; q++)
                acc = fmaf(W[q * D + k], av[q], acc);
            vab[half * D + k] = acc;
        } else {
            int t2 = tid - 256;     // 256 float4 = 8 rows x 128
            ((float4*)hls)[t2] = ((const float4*)(h + i0 * D))[t2];
        }
        __syncthreads();
        int g = tid >> 6, l = tid & 63;      // 8 rows x 64 lanes
        float h0 = hls[g * D + l], h1 = hls[g * D + 64 + l];
        float p1 = fmaf(h0, vab[l], h1 * vab[64 + l]);
        float p2 = fmaf(h0, vab[D + l], h1 * vab[D + 64 + l]);
        #pragma unroll
        for (int off = 32; off > 0; off >>= 1) {
            p1 += __shfl_xor(p1, off);
            p2 += __shfl_xor(p2, off);
        }
        if (l == 0) { s1[i0 + g] = p1; s2[i0 + g] = p2; }
    }

    grid.sync();

    // ========================= A2: base rows 4b..4b+3 =========================
    {
        if (tid < 128) ((float4*)tl)[tid] = ((const float4*)(h + b * MROWS * D))[tid];
        __syncthreads();
        int r = tid >> 7, d = tid & 127;
        float acc = b1[d];
        #pragma unroll 8
        for (int k = 0; k < D; k++)
            acc = fmaf(tl[r][k], Mt[k * D + d], acc);
        base[(b * MROWS + r) * D + d] = acc;
    }

    grid.sync();

    // ========================= B: mega =========================
    float (*bl)[MJC][D]     = (float (*)[MJC][D])pool;
    float (*racc)[MROWS][D] = (float (*)[MROWS][D])pool;
    const int i0 = b * MROWS;

    // issue chunk-0 staging loads early (hide HBM under alpha phase)
    float4 pre0, pre1, pre2, pre3;
    float ppd = 0.f, put = 0.f;
    {
        const float4* src = (const float4*)base;     // chunk 0: j0 = 0
        pre0 = src[tid];        pre1 = src[tid + 512];
        pre2 = src[tid + 1024]; pre3 = src[tid + 1536];
        if (tid < 256) {
            int rr = tid >> 6, jj = tid & 63;
            ppd = pd[(i0 + rr) * N + jj];
            put = ut[(i0 + rr) * N + jj];
        }
    }

    // phase 0: alpha (row r <-> threads [128r,128r+128) = waves 2r,2r+1)
    {
        int r = tid >> 7;
        int i = i0 + r;
        int jb = (tid & 127) * 8;
        float s1i = s1[i];
        float4 sa = *(const float4*)&s2[jb];
        float4 sb = *(const float4*)&s2[jb + 4];
        int4 ma = *(const int4*)&adj[i * N + jb];
        int4 mb = *(const int4*)&adj[i * N + jb + 4];
        float e[8]; int mm[8];
        e[0]=s1i+sa.x; e[1]=s1i+sa.y; e[2]=s1i+sa.z; e[3]=s1i+sa.w;
        e[4]=s1i+sb.x; e[5]=s1i+sb.y; e[6]=s1i+sb.z; e[7]=s1i+sb.w;
        mm[0]=ma.x; mm[1]=ma.y; mm[2]=ma.z; mm[3]=ma.w;
        mm[4]=mb.x; mm[5]=mb.y; mm[6]=mb.z; mm[7]=mb.w;
        float mx = -3e38f;
        #pragma unroll
        for (int q = 0; q < 8; q++) {
            e[q] = e[q] > 0.f ? e[q] : LEAK * e[q];
            if (mm[q] > 0) mx = fmaxf(mx, e[q]);
        }
        #pragma unroll
        for (int off = 32; off > 0; off >>= 1) mx = fmaxf(mx, __shfl_xor(mx, off));
        int wid = tid >> 6, lane = tid & 63;
        if (lane == 0) red[wid] = mx;
        __syncthreads();
        mx = fmaxf(red[2 * r], red[2 * r + 1]);
        float ev[8]; float sum = 0.f;
        #pragma unroll
        for (int q = 0; q < 8; q++) {
            ev[q] = (mm[q] > 0) ? __expf(e[q] - mx) : 0.f;
            sum += ev[q];
        }
        #pragma unroll
        for (int off = 32; off > 0; off >>= 1) sum += __shfl_xor(sum, off);
        if (lane == 0) red2[wid] = sum;
        __syncthreads();
        sum = red2[2 * r] + red2[2 * r + 1];
        float inv = sum > 0.f ? 1.f / sum : 0.f;
        *(float4*)&al[r][jb]     = make_float4(ev[0]*inv, ev[1]*inv, ev[2]*inv, ev[3]*inv);
        *(float4*)&al[r][jb + 4] = make_float4(ev[4]*inv, ev[5]*inv, ev[6]*inv, ev[7]*inv);
        if ((tid & 127) == 0) gsum[r] = sum;
    }
    __syncthreads();

    // commit chunk 0
    {
        float4* dst = (float4*)bl[0];
        dst[tid] = pre0; dst[tid + 512] = pre1;
        dst[tid + 1024] = pre2; dst[tid + 1536] = pre3;
        if (tid < 256) {
            int rr = tid >> 6, jj = tid & 63;
            sc[0][rr][jj] = make_float4(ppd, put, al[rr][jj], 0.f);
        }
    }
    __syncthreads();

    const int l16 = tid & 15, g = tid >> 4;       // 32 groups x 16 lanes
    const int k0a = l16 * 4, k0b = 64 + l16 * 4;  // split-k: 8 k's per lane
    const float4 wp0 = *(const float4*)&wpd[k0a];
    const float4 wp1 = *(const float4*)&wpd[k0b];
    const float4 wu0 = *(const float4*)&wut[k0a];
    const float4 wu1 = *(const float4*)&wut[k0b];

    float4 a0[MROWS] = {}, a1[MROWS] = {};

    for (int c = 0; c < NCHUNK; c++) {
        int cb = c & 1;
        if (c + 1 < NCHUNK) {
            const float4* src = (const float4*)(base + (c + 1) * MJC * D);
            pre0 = src[tid];        pre1 = src[tid + 512];
            pre2 = src[tid + 1024]; pre3 = src[tid + 1536];
            if (tid < 256) {
                int rr = tid >> 6, jj = tid & 63;
                ppd = pd[(i0 + rr) * N + (c + 1) * MJC + jj];
                put = ut[(i0 + rr) * N + (c + 1) * MJC + jj];
            }
        }
        #pragma unroll
        for (int jj2 = 0; jj2 < 2; jj2++) {
            int jl = g * 2 + jj2;
            float4 b0  = *(const float4*)&bl[cb][jl][k0a];
            float4 b1v = *(const float4*)&bl[cb][jl][k0b];
            #pragma unroll
            for (int r = 0; r < MROWS; r++) {
                float4 s = sc[cb][r][jl];
                float v;
                v = fmaxf(fmaf(s.x, wp0.x, fmaf(s.y, wu0.x, b0.x)), 0.f);  a0[r].x = fmaf(s.z, v, a0[r].x);
                v = fmaxf(fmaf(s.x, wp0.y, fmaf(s.y, wu0.y, b0.y)), 0.f);  a0[r].y = fmaf(s.z, v, a0[r].y);
                v = fmaxf(fmaf(s.x, wp0.z, fmaf(s.y, wu0.z, b0.z)), 0.f);  a0[r].z = fmaf(s.z, v, a0[r].z);
                v = fmaxf(fmaf(s.x, wp0.w, fmaf(s.y, wu0.w, b0.w)), 0.f);  a0[r].w = fmaf(s.z, v, a0[r].w);
                v = fmaxf(fmaf(s.x, wp1.x, fmaf(s.y, wu1.x, b1v.x)), 0.f); a1[r].x = fmaf(s.z, v, a1[r].x);
                v = fmaxf(fmaf(s.x, wp1.y, fmaf(s.y, wu1.y, b1v.y)), 0.f); a1[r].y = fmaf(s.z, v, a1[r].y);
                v = fmaxf(fmaf(s.x, wp1.z, fmaf(s.y, wu1.z, b1v.z)), 0.f); a1[r].z = fmaf(s.z, v, a1[r].z);
                v = fmaxf(fmaf(s.x, wp1.w, fmaf(s.y, wu1.w, b1v.w)), 0.f); a1[r].w = fmaf(s.z, v, a1[r].w);
            }
        }
        if (c + 1 < NCHUNK) {
            int nb = (c + 1) & 1;
            float4* dst = (float4*)bl[nb];
            dst[tid] = pre0; dst[tid + 512] = pre1;
            dst[tid + 1024] = pre2; dst[tid + 1536] = pre3;
            if (tid < 256) {
                int rr = tid >> 6, jj = tid & 63;
                sc[nb][rr][jj] = make_float4(ppd, put, al[rr][(c + 1) * MJC + jj], 0.f);
            }
        }
        __syncthreads();
    }

    // cross-group reduce (racc overlays bl; all compute done)
    #pragma unroll
    for (int r = 0; r < MROWS; r++) {
        *(float4*)&racc[g][r][k0a] = a0[r];
        *(float4*)&racc[g][r][k0b] = a1[r];
    }
    __syncthreads();
    {
        int rr = tid >> 7, k = tid & 127;
        float v = 0.f;
        #pragma unroll
        for (int g2 = 0; g2 < 32; g2++) v += racc[g2][rr][k];
        tl[rr][k] = v;
    }
    __syncthreads();
    // final GEMM: out[i][d] = sum_k t[k] * W2t[k][d] + gate*b2[d]
    {
        int rr = tid >> 7, d = tid & 127;
        float acc = (gsum[rr] > 0.f) ? b2[d] : 0.f;
        #pragma unroll 8
        for (int k = 0; k < D; k++)
            acc = fmaf(tl[rr][k], W2t[k * D + d], acc);
        out[(i0 + rr) * D + d] = acc;
    }
}

// ---------------------------------------------------------------------------
extern "C" void kernel_launch(void* const* d_in, const int* in_sizes, int n_in,
                              void* d_out, int out_size, void* d_ws, size_t ws_size,
                              hipStream_t stream) {
    (void)in_sizes; (void)n_in; (void)out_size; (void)ws_size;
    const float* h   = (const float*)d_in[0];
    const int*   adj = (const int*)d_in[1];
    const float* pd  = (const float*)d_in[2];
    const float* ut  = (const float*)d_in[3];
    const float* W   = (const float*)d_in[4];
    const float* a   = (const float*)d_in[5];
    const float* W1  = (const float*)d_in[6];
    const float* b1  = (const float*)d_in[7];
    const float* W2  = (const float*)d_in[8];
    const float* b2  = (const float*)d_in[9];
    float* out = (float*)d_out;
    float* ws = (float*)d_ws;

    float* Mt    = ws + OFF_MT;
    float* W2t   = ws + OFF_W2T;
    float* wpd   = ws + OFF_WPD;
    float* wut   = ws + OFF_WUT;
    float* s1    = ws + OFF_S1;
    float* s2    = ws + OFF_S2;
    float* baseb = ws + OFF_BASE;

    void* args[] = {
        (void*)&h, (void*)&adj, (void*)&pd, (void*)&ut, (void*)&W, (void*)&a,
        (void*)&W1, (void*)&b1, (void*)&W2, (void*)&b2,
        (void*)&Mt, (void*)&W2t, (void*)&wpd, (void*)&wut,
        (void*)&s1, (void*)&s2, (void*)&baseb, (void*)&out
    };
    hipLaunchCooperativeKernel((const void*)fused_kernel, dim3(256), dim3(512),
                               args, 0, stream);
}

// Round 7
// 46.977 us; speedup vs baseline: 2.4010x; 2.4010x over previous
//
#include <hip/hip_runtime.h>
#include <hip/hip_bf16.h>

#define N 1024
#define D 128
#define LEAK 0.2f

#define MROWS 4          // i-rows per mega block
#define MJC 64           // j chunk
#define NCHUNK (N / MJC) // 16

// workspace layout (float offsets)
#define OFF_MT   0
#define OFF_W2T  16384
#define OFF_WPD  32768
#define OFF_WUT  32896
#define OFF_S1   33024
#define OFF_S2   34048
#define OFF_BASE 35072

// ---------------------------------------------------------------------------
// K1: heterogeneous prep (unchanged from round 5).
//   b 0..63   : Mt rows 2b,2b+1   (Mt = (W1h @ W)^T, so base = h @ Mt)
//   b 64..67  : W2t 32-row tile
//   b 68      : wpd/wut extraction
//   b 69..196 : s1/s2 for rows (b-69)*8..
__global__ __launch_bounds__(256) void prep_kernel(
    const float* __restrict__ W, const float* __restrict__ W1,
    const float* __restrict__ W2, const float* __restrict__ a,
    const float* __restrict__ h,
    float* __restrict__ Mt, float* __restrict__ W2t,
    float* __restrict__ wpd, float* __restrict__ wut,
    float* __restrict__ s1, float* __restrict__ s2) {
    __shared__ float lds[128 * 129];
    int b = blockIdx.x, tid = threadIdx.x;
    if (b < 64) {
        int k0 = 2 * b;
        int col = tid & 127, half = tid >> 7;
        #pragma unroll 8
        for (int p = 0; p < 64; p++) {
            int row = 2 * p + half;
            lds[row * 129 + col] = W1[row * (D + 2) + col];
        }
        __syncthreads();
        int d = tid & 127, kl = tid >> 7;
        int k = k0 + kl;
        float acc = 0.f;
        #pragma unroll 8
        for (int q = 0; q < D; q++)
            acc = fmaf(lds[d * 129 + q], W[q * D + k], acc);
        Mt[k * D + d] = acc;
    } else if (b < 68) {
        int kbase = 32 * (b - 64);
        #pragma unroll
        for (int p = 0; p < 16; p++) {
            int idx = tid + p * 256;
            int rd = idx >> 5, cc = idx & 31;
            lds[cc * 129 + rd] = W2[rd * D + kbase + cc];
        }
        __syncthreads();
        #pragma unroll
        for (int p = 0; p < 16; p++) {
            int idx = tid + p * 256;
            int kl = idx >> 7, dd = idx & 127;
            W2t[(kbase + kl) * D + dd] = lds[kl * 129 + dd];
        }
    } else if (b == 68) {
        if (tid < 128) wpd[tid] = W1[tid * (D + 2) + D];
        else           wut[tid - 128] = W1[(tid - 128) * (D + 2) + D + 1];
    } else {
        float* vab = lds;            // [2][128]
        float* hls = lds + 256;      // [8][128]
        int i0 = (b - 69) * 8;
        {
            int half = tid >> 7, k = tid & 127;
            const float* av = a + half * D;
            float acc = 0.f;
            #pragma unroll 8
            for (int q = 0; q < D; q++)
                acc = fmaf(W[q * D + k], av[q], acc);
            vab[half * D + k] = acc;
        }
        ((float4*)hls)[tid] = ((const float4*)(h + i0 * D))[tid];
        __syncthreads();
        int g32 = tid >> 5, l32 = tid & 31;
        float p1 = 0.f, p2 = 0.f;
        #pragma unroll
        for (int q = 0; q < 4; q++) {
            float hv = hls[g32 * D + l32 + 32 * q];
            p1 = fmaf(hv, vab[l32 + 32 * q], p1);
            p2 = fmaf(hv, vab[D + l32 + 32 * q], p2);
        }
        #pragma unroll
        for (int off = 16; off > 0; off >>= 1) {
            p1 += __shfl_xor(p1, off);
            p2 += __shfl_xor(p2, off);
        }
        if (l32 == 0) { s1[i0 + g32] = p1; s2[i0 + g32] = p2; }
    }
}

// ---------------------------------------------------------------------------
// K2: base[i][d] = b1[d] + sum_k h[i][k] Mt[k][d]   (unchanged from round 5)
__global__ __launch_bounds__(256) void base_kernel(
    const float* __restrict__ h, const float* __restrict__ Mt,
    const float* __restrict__ b1, float* __restrict__ base) {
    __shared__ float hl[8][D];
    int tid = threadIdx.x;
    int i0 = blockIdx.x * 8;
    ((float4*)hl)[tid] = ((const float4*)(h + i0 * D))[tid];
    __syncthreads();
    int g = tid >> 5, d0 = (tid & 31) * 4;
    float4 acc = *(const float4*)&b1[d0];
    #pragma unroll 8
    for (int k = 0; k < D; k++) {
        float4 m = *(const float4*)&Mt[k * D + d0];
        float hb = hl[g][k];
        acc.x = fmaf(hb, m.x, acc.x);
        acc.y = fmaf(hb, m.y, acc.y);
        acc.z = fmaf(hb, m.z, acc.z);
        acc.w = fmaf(hb, m.w, acc.w);
    }
    *(float4*)&base[(i0 + g) * D + d0] = acc;
}

// ---------------------------------------------------------------------------
// K3: mega at 1024 threads (16 waves/block = 4 waves/SIMD; 2x the TLP of r5).
//   64 groups x 16 lanes; group g owns j-local g; k-slice rotated by (l16+g)&15
//   so bl reads are bank-conflict-free.
__global__ __launch_bounds__(1024, 4) void mega_kernel(
    const float* __restrict__ base, const float* __restrict__ s1,
    const float* __restrict__ s2, const int* __restrict__ adj,
    const float* __restrict__ pd, const float* __restrict__ ut,
    const float* __restrict__ wpd, const float* __restrict__ wut,
    const float* __restrict__ W2t, const float* __restrict__ b2,
    float* __restrict__ out) {
    __shared__ float pool[16384];          // 64KB: bl[2][64][128] | racc[32][4][128]
    __shared__ float al[MROWS][N];         // 16KB alpha
    __shared__ float4 sc[2][MROWS][MJC];   // 8KB {pd, ut, alpha, 0}
    __shared__ float red[16], red2[16], gsum[MROWS];
    __shared__ float tl[MROWS][D];

    float (*bl)[MJC][D]     = (float (*)[MJC][D])pool;
    float (*racc)[MROWS][D] = (float (*)[MROWS][D])pool;

    const int tid = threadIdx.x;           // 0..1023
    const int i0 = blockIdx.x * MROWS;

    // ---- issue chunk-0 staging loads early (hide HBM under alpha phase) ----
    float4 pre0, pre1;
    float ppd = 0.f, put = 0.f;
    {
        const float4* src = (const float4*)base;     // chunk 0: j0 = 0
        pre0 = src[tid]; pre1 = src[tid + 1024];
        if (tid < 256) {
            int rr = tid >> 6, jj = tid & 63;
            ppd = pd[(i0 + rr) * N + jj];
            put = ut[(i0 + rr) * N + jj];
        }
    }

    // ---- phase 0: alpha (row r <-> 256 threads = waves 4r..4r+3) ----
    {
        int r = tid >> 8;
        int i = i0 + r;
        int jb = (tid & 255) * 4;
        float s1i = s1[i];
        float4 sa = *(const float4*)&s2[jb];
        int4 ma = *(const int4*)&adj[i * N + jb];
        float e[4]; int mm[4];
        e[0] = s1i + sa.x; e[1] = s1i + sa.y; e[2] = s1i + sa.z; e[3] = s1i + sa.w;
        mm[0] = ma.x; mm[1] = ma.y; mm[2] = ma.z; mm[3] = ma.w;
        float mx = -3e38f;
        #pragma unroll
        for (int q = 0; q < 4; q++) {
            e[q] = e[q] > 0.f ? e[q] : LEAK * e[q];
            if (mm[q] > 0) mx = fmaxf(mx, e[q]);
        }
        #pragma unroll
        for (int off = 32; off > 0; off >>= 1) mx = fmaxf(mx, __shfl_xor(mx, off));
        int wid = tid >> 6, lane = tid & 63;
        if (lane == 0) red[wid] = mx;
        __syncthreads();
        mx = fmaxf(fmaxf(red[4 * r], red[4 * r + 1]),
                   fmaxf(red[4 * r + 2], red[4 * r + 3]));
        float ev[4]; float sum = 0.f;
        #pragma unroll
        for (int q = 0; q < 4; q++) {
            ev[q] = (mm[q] > 0) ? __expf(e[q] - mx) : 0.f;
            sum += ev[q];
        }
        #pragma unroll
        for (int off = 32; off > 0; off >>= 1) sum += __shfl_xor(sum, off);
        if (lane == 0) red2[wid] = sum;
        __syncthreads();
        sum = red2[4 * r] + red2[4 * r + 1] + red2[4 * r + 2] + red2[4 * r + 3];
        float inv = sum > 0.f ? 1.f / sum : 0.f;
        *(float4*)&al[r][jb] = make_float4(ev[0] * inv, ev[1] * inv, ev[2] * inv, ev[3] * inv);
        if ((tid & 255) == 0) gsum[r] = sum;
    }
    __syncthreads();

    // ---- commit chunk 0 ----
    {
        float4* dst = (float4*)bl[0];
        dst[tid] = pre0; dst[tid + 1024] = pre1;
        if (tid < 256) {
            int rr = tid >> 6, jj = tid & 63;
            sc[0][rr][jj] = make_float4(ppd, put, al[rr][jj], 0.f);
        }
    }
    __syncthreads();

    const int l16 = tid & 15, g = tid >> 4;        // 64 groups x 16 lanes
    const int rot = (l16 + g) & 15;                // conflict-free bl reads
    const int k0a = rot * 4, k0b = 64 + rot * 4;
    const float4 wp0 = *(const float4*)&wpd[k0a];
    const float4 wp1 = *(const float4*)&wpd[k0b];
    const float4 wu0 = *(const float4*)&wut[k0a];
    const float4 wu1 = *(const float4*)&wut[k0b];

    float4 a0[MROWS] = {}, a1[MROWS] = {};

    for (int c = 0; c < NCHUNK; c++) {
        int cb = c & 1;
        // issue next-chunk staging (overlaps compute below)
        if (c + 1 < NCHUNK) {
            const float4* src = (const float4*)(base + (c + 1) * MJC * D);
            pre0 = src[tid]; pre1 = src[tid + 1024];
            if (tid < 256) {
                int rr = tid >> 6, jj = tid & 63;
                ppd = pd[(i0 + rr) * N + (c + 1) * MJC + jj];
                put = ut[(i0 + rr) * N + (c + 1) * MJC + jj];
            }
        }
        // compute chunk c: group g owns j-local g
        {
            float4 b0  = *(const float4*)&bl[cb][g][k0a];
            float4 b1v = *(const float4*)&bl[cb][g][k0b];
            #pragma unroll
            for (int r = 0; r < MROWS; r++) {
                float4 s = sc[cb][r][g];
                float v;
                v = fmaxf(fmaf(s.x, wp0.x, fmaf(s.y, wu0.x, b0.x)), 0.f);  a0[r].x = fmaf(s.z, v, a0[r].x);
                v = fmaxf(fmaf(s.x, wp0.y, fmaf(s.y, wu0.y, b0.y)), 0.f);  a0[r].y = fmaf(s.z, v, a0[r].y);
                v = fmaxf(fmaf(s.x, wp0.z, fmaf(s.y, wu0.z, b0.z)), 0.f);  a0[r].z = fmaf(s.z, v, a0[r].z);
                v = fmaxf(fmaf(s.x, wp0.w, fmaf(s.y, wu0.w, b0.w)), 0.f);  a0[r].w = fmaf(s.z, v, a0[r].w);
                v = fmaxf(fmaf(s.x, wp1.x, fmaf(s.y, wu1.x, b1v.x)), 0.f); a1[r].x = fmaf(s.z, v, a1[r].x);
                v = fmaxf(fmaf(s.x, wp1.y, fmaf(s.y, wu1.y, b1v.y)), 0.f); a1[r].y = fmaf(s.z, v, a1[r].y);
                v = fmaxf(fmaf(s.x, wp1.z, fmaf(s.y, wu1.z, b1v.z)), 0.f); a1[r].z = fmaf(s.z, v, a1[r].z);
                v = fmaxf(fmaf(s.x, wp1.w, fmaf(s.y, wu1.w, b1v.w)), 0.f); a1[r].w = fmaf(s.z, v, a1[r].w);
            }
        }
        // commit next chunk into the other buffer
        if (c + 1 < NCHUNK) {
            int nb = (c + 1) & 1;
            float4* dst = (float4*)bl[nb];
            dst[tid] = pre0; dst[tid + 1024] = pre1;
            if (tid < 256) {
                int rr = tid >> 6, jj = tid & 63;
                sc[nb][rr][jj] = make_float4(ppd, put, al[rr][(c + 1) * MJC + jj], 0.f);
            }
        }
        __syncthreads();
    }

    // ---- cross-group reduce: 64 groups -> 32 slots -> tl (racc overlays bl) ----
    if (g < 32) {
        #pragma unroll
        for (int r = 0; r < MROWS; r++) {
            *(float4*)&racc[g][r][k0a] = a0[r];
            *(float4*)&racc[g][r][k0b] = a1[r];
        }
    }
    __syncthreads();
    if (g >= 32) {
        int g2 = g - 32;
        #pragma unroll
        for (int r = 0; r < MROWS; r++) {
            float4 t0 = *(const float4*)&racc[g2][r][k0a];
            float4 t1 = *(const float4*)&racc[g2][r][k0b];
            t0.x += a0[r].x; t0.y += a0[r].y; t0.z += a0[r].z; t0.w += a0[r].w;
            t1.x += a1[r].x; t1.y += a1[r].y; t1.z += a1[r].z; t1.w += a1[r].w;
            *(float4*)&racc[g2][r][k0a] = t0;
            *(float4*)&racc[g2][r][k0b] = t1;
        }
    }
    __syncthreads();
    if (tid < 512) {
        int rr = tid >> 7, k = tid & 127;
        float v = 0.f;
        #pragma unroll
        for (int g2 = 0; g2 < 32; g2++) v += racc[g2][rr][k];
        tl[rr][k] = v;
    }
    __syncthreads();
    // ---- final GEMM: out[i][d] = sum_k t[k] * W2t[k][d] + gate*b2[d] ----
    if (tid < 512) {
        int rr = tid >> 7, d = tid & 127;
        float acc = (gsum[rr] > 0.f) ? b2[d] : 0.f;
        #pragma unroll 8
        for (int k = 0; k < D; k++)
            acc = fmaf(tl[rr][k], W2t[k * D + d], acc);
        out[(i0 + rr) * D + d] = acc;
    }
}

// ---------------------------------------------------------------------------
extern "C" void kernel_launch(void* const* d_in, const int* in_sizes, int n_in,
                              void* d_out, int out_size, void* d_ws, size_t ws_size,
                              hipStream_t stream) {
    (void)in_sizes; (void)n_in; (void)out_size; (void)ws_size;
    const float* h   = (const float*)d_in[0];
    const int*   adj = (const int*)d_in[1];
    const float* pd  = (const float*)d_in[2];
    const float* ut  = (const float*)d_in[3];
    const float* W   = (const float*)d_in[4];
    const float* a   = (const float*)d_in[5];
    const float* W1  = (const float*)d_in[6];
    const float* b1  = (const float*)d_in[7];
    const float* W2  = (const float*)d_in[8];
    const float* b2  = (const float*)d_in[9];
    float* out = (float*)d_out;
    float* ws = (float*)d_ws;

    float* Mt    = ws + OFF_MT;
    float* W2t   = ws + OFF_W2T;
    float* wpd   = ws + OFF_WPD;
    float* wut   = ws + OFF_WUT;
    float* s1    = ws + OFF_S1;
    float* s2    = ws + OFF_S2;
    float* baseb = ws + OFF_BASE;

    prep_kernel<<<197, 256, 0, stream>>>(W, W1, W2, a, h, Mt, W2t, wpd, wut, s1, s2);
    base_kernel<<<128, 256, 0, stream>>>(h, Mt, b1, baseb);
    mega_kernel<<<N / MROWS, 1024, 0, stream>>>(baseb, s1, s2, adj, pd, ut,
                                                wpd, wut, W2t, b2, out);
}

// Round 8
// 46.504 us; speedup vs baseline: 2.4254x; 1.0102x over previous
//
#include <hip/hip_runtime.h>
#include <hip/hip_bf16.h>

#define N 1024
#define D 128
#define LEAK 0.2f

#define MROWS 4          // i-rows per mega block
#define MJC 64           // j chunk
#define NCHUNK (N / MJC) // 16

// workspace layout (float offsets)
#define OFF_W2T  0
#define OFF_WPD  16384
#define OFF_WUT  16512
#define OFF_S1   16640
#define OFF_S2   17664
#define OFF_BASE 18688

// ---------------------------------------------------------------------------
// K_A: prep + base fused (no Mt intermediate -> no kernel boundary).
//   b 0..255 : rows 4b..4b+3:  Wh = h@W^T (LDS), s1/s2 = Wh@a, base = Wh@W1h^T + b1
//   b 256..259: W2t 32-row tile (W2t[k][d] = W2[d][k])
//   b 260     : wpd/wut extraction
__global__ __launch_bounds__(256) void prep_base_kernel(
    const float* __restrict__ W, const float* __restrict__ W1,
    const float* __restrict__ W2, const float* __restrict__ a,
    const float* __restrict__ h, const float* __restrict__ b1,
    float* __restrict__ W2t, float* __restrict__ wpd, float* __restrict__ wut,
    float* __restrict__ s1, float* __restrict__ s2, float* __restrict__ base) {
    __shared__ float pool[4160];   // 16.6 KB: base branch [4][128]x2 | W2t branch 129-stride
    int b = blockIdx.x, tid = threadIdx.x;
    if (b < 256) {
        float* hl  = pool;          // [4][128]
        float* whl = pool + 512;    // [4][128]
        int i0 = b * 4;
        if (tid < 128) ((float4*)hl)[tid] = ((const float4*)(h + i0 * D))[tid];
        __syncthreads();
        int r = tid >> 6, l = tid & 63;
        // ---- Wh[r][2l], Wh[r][2l+1] ----
        int k0 = l * 2;
        float u0 = 0.f, u1 = 0.f;
        #pragma unroll 8
        for (int q = 0; q < D; q += 4) {
            float4 hq = *(const float4*)&hl[r * D + q];
            float4 w0 = *(const float4*)&W[k0 * D + q];
            float4 w1 = *(const float4*)&W[(k0 + 1) * D + q];
            u0 = fmaf(hq.x, w0.x, u0); u0 = fmaf(hq.y, w0.y, u0);
            u0 = fmaf(hq.z, w0.z, u0); u0 = fmaf(hq.w, w0.w, u0);
            u1 = fmaf(hq.x, w1.x, u1); u1 = fmaf(hq.y, w1.y, u1);
            u1 = fmaf(hq.z, w1.z, u1); u1 = fmaf(hq.w, w1.w, u1);
        }
        whl[r * D + k0] = u0;
        whl[r * D + k0 + 1] = u1;
        __syncthreads();
        // ---- s1/s2 = Wh @ a (full-wave reduce, wave r owns row r) ----
        {
            float w0 = whl[r * D + l], w1 = whl[r * D + 64 + l];
            float p1 = fmaf(w0, a[l], w1 * a[64 + l]);
            float p2 = fmaf(w0, a[D + l], w1 * a[D + 64 + l]);
            #pragma unroll
            for (int off = 32; off > 0; off >>= 1) {
                p1 += __shfl_xor(p1, off);
                p2 += __shfl_xor(p2, off);
            }
            if (l == 0) { s1[i0 + r] = p1; s2[i0 + r] = p2; }
        }
        // ---- base[r][2l], base[r][2l+1]  (W1 rows are 130 floats: float2-aligned) ----
        int d0 = l * 2;
        float a0 = b1[d0], a1 = b1[d0 + 1];
        #pragma unroll 8
        for (int q = 0; q < D; q += 2) {
            float2 wh2 = *(const float2*)&whl[r * D + q];
            float2 x0 = *(const float2*)&W1[d0 * (D + 2) + q];
            float2 x1 = *(const float2*)&W1[(d0 + 1) * (D + 2) + q];
            a0 = fmaf(wh2.x, x0.x, a0); a0 = fmaf(wh2.y, x0.y, a0);
            a1 = fmaf(wh2.x, x1.x, a1); a1 = fmaf(wh2.y, x1.y, a1);
        }
        *(float2*)&base[(i0 + r) * D + d0] = make_float2(a0, a1);
    } else if (b < 260) {
        int kbase = 32 * (b - 256);
        #pragma unroll
        for (int p = 0; p < 16; p++) {
            int idx = tid + p * 256;
            int rd = idx >> 5, cc = idx & 31;
            pool[cc * 129 + rd] = W2[rd * D + kbase + cc];
        }
        __syncthreads();
        #pragma unroll
        for (int p = 0; p < 16; p++) {
            int idx = tid + p * 256;
            int kl = idx >> 7, dd = idx & 127;
            W2t[(kbase + kl) * D + dd] = pool[kl * 129 + dd];
        }
    } else {
        if (tid < 128) wpd[tid] = W1[tid * (D + 2) + D];
        else           wut[tid - 128] = W1[(tid - 128) * (D + 2) + D + 1];
    }
}

// ---------------------------------------------------------------------------
// K_B: mega (byte-identical to round 7).
__global__ __launch_bounds__(1024, 4) void mega_kernel(
    const float* __restrict__ base, const float* __restrict__ s1,
    const float* __restrict__ s2, const int* __restrict__ adj,
    const float* __restrict__ pd, const float* __restrict__ ut,
    const float* __restrict__ wpd, const float* __restrict__ wut,
    const float* __restrict__ W2t, const float* __restrict__ b2,
    float* __restrict__ out) {
    __shared__ float pool[16384];          // 64KB: bl[2][64][128] | racc[32][4][128]
    __shared__ float al[MROWS][N];         // 16KB alpha
    __shared__ float4 sc[2][MROWS][MJC];   // 8KB {pd, ut, alpha, 0}
    __shared__ float red[16], red2[16], gsum[MROWS];
    __shared__ float tl[MROWS][D];

    float (*bl)[MJC][D]     = (float (*)[MJC][D])pool;
    float (*racc)[MROWS][D] = (float (*)[MROWS][D])pool;

    const int tid = threadIdx.x;           // 0..1023
    const int i0 = blockIdx.x * MROWS;

    // ---- issue chunk-0 staging loads early (hide HBM under alpha phase) ----
    float4 pre0, pre1;
    float ppd = 0.f, put = 0.f;
    {
        const float4* src = (const float4*)base;     // chunk 0: j0 = 0
        pre0 = src[tid]; pre1 = src[tid + 1024];
        if (tid < 256) {
            int rr = tid >> 6, jj = tid & 63;
            ppd = pd[(i0 + rr) * N + jj];
            put = ut[(i0 + rr) * N + jj];
        }
    }

    // ---- phase 0: alpha (row r <-> 256 threads = waves 4r..4r+3) ----
    {
        int r = tid >> 8;
        int i = i0 + r;
        int jb = (tid & 255) * 4;
        float s1i = s1[i];
        float4 sa = *(const float4*)&s2[jb];
        int4 ma = *(const int4*)&adj[i * N + jb];
        float e[4]; int mm[4];
        e[0] = s1i + sa.x; e[1] = s1i + sa.y; e[2] = s1i + sa.z; e[3] = s1i + sa.w;
        mm[0] = ma.x; mm[1] = ma.y; mm[2] = ma.z; mm[3] = ma.w;
        float mx = -3e38f;
        #pragma unroll
        for (int q = 0; q < 4; q++) {
            e[q] = e[q] > 0.f ? e[q] : LEAK * e[q];
            if (mm[q] > 0) mx = fmaxf(mx, e[q]);
        }
        #pragma unroll
        for (int off = 32; off > 0; off >>= 1) mx = fmaxf(mx, __shfl_xor(mx, off));
        int wid = tid >> 6, lane = tid & 63;
        if (lane == 0) red[wid] = mx;
        __syncthreads();
        mx = fmaxf(fmaxf(red[4 * r], red[4 * r + 1]),
                   fmaxf(red[4 * r + 2], red[4 * r + 3]));
        float ev[4]; float sum = 0.f;
        #pragma unroll
        for (int q = 0; q < 4; q++) {
            ev[q] = (mm[q] > 0) ? __expf(e[q] - mx) : 0.f;
            sum += ev[q];
        }
        #pragma unroll
        for (int off = 32; off > 0; off >>= 1) sum += __shfl_xor(sum, off);
        if (lane == 0) red2[wid] = sum;
        __syncthreads();
        sum = red2[4 * r] + red2[4 * r + 1] + red2[4 * r + 2] + red2[4 * r + 3];
        float inv = sum > 0.f ? 1.f / sum : 0.f;
        *(float4*)&al[r][jb] = make_float4(ev[0] * inv, ev[1] * inv, ev[2] * inv, ev[3] * inv);
        if ((tid & 255) == 0) gsum[r] = sum;
    }
    __syncthreads();

    // ---- commit chunk 0 ----
    {
        float4* dst = (float4*)bl[0];
        dst[tid] = pre0; dst[tid + 1024] = pre1;
        if (tid < 256) {
            int rr = tid >> 6, jj = tid & 63;
            sc[0][rr][jj] = make_float4(ppd, put, al[rr][jj], 0.f);
        }
    }
    __syncthreads();

    const int l16 = tid & 15, g = tid >> 4;        // 64 groups x 16 lanes
    const int rot = (l16 + g) & 15;                // conflict-free bl reads
    const int k0a = rot * 4, k0b = 64 + rot * 4;
    const float4 wp0 = *(const float4*)&wpd[k0a];
    const float4 wp1 = *(const float4*)&wpd[k0b];
    const float4 wu0 = *(const float4*)&wut[k0a];
    const float4 wu1 = *(const float4*)&wut[k0b];

    float4 a0[MROWS] = {}, a1[MROWS] = {};

    for (int c = 0; c < NCHUNK; c++) {
        int cb = c & 1;
        if (c + 1 < NCHUNK) {
            const float4* src = (const float4*)(base + (c + 1) * MJC * D);
            pre0 = src[tid]; pre1 = src[tid + 1024];
            if (tid < 256) {
                int rr = tid >> 6, jj = tid & 63;
                ppd = pd[(i0 + rr) * N + (c + 1) * MJC + jj];
                put = ut[(i0 + rr) * N + (c + 1) * MJC + jj];
            }
        }
        {
            float4 b0  = *(const float4*)&bl[cb][g][k0a];
            float4 b1v = *(const float4*)&bl[cb][g][k0b];
            #pragma unroll
            for (int r = 0; r < MROWS; r++) {
                float4 s = sc[cb][r][g];
                float v;
                v = fmaxf(fmaf(s.x, wp0.x, fmaf(s.y, wu0.x, b0.x)), 0.f);  a0[r].x = fmaf(s.z, v, a0[r].x);
                v = fmaxf(fmaf(s.x, wp0.y, fmaf(s.y, wu0.y, b0.y)), 0.f);  a0[r].y = fmaf(s.z, v, a0[r].y);
                v = fmaxf(fmaf(s.x, wp0.z, fmaf(s.y, wu0.z, b0.z)), 0.f);  a0[r].z = fmaf(s.z, v, a0[r].z);
                v = fmaxf(fmaf(s.x, wp0.w, fmaf(s.y, wu0.w, b0.w)), 0.f);  a0[r].w = fmaf(s.z, v, a0[r].w);
                v = fmaxf(fmaf(s.x, wp1.x, fmaf(s.y, wu1.x, b1v.x)), 0.f); a1[r].x = fmaf(s.z, v, a1[r].x);
                v = fmaxf(fmaf(s.x, wp1.y, fmaf(s.y, wu1.y, b1v.y)), 0.f); a1[r].y = fmaf(s.z, v, a1[r].y);
                v = fmaxf(fmaf(s.x, wp1.z, fmaf(s.y, wu1.z, b1v.z)), 0.f); a1[r].z = fmaf(s.z, v, a1[r].z);
                v = fmaxf(fmaf(s.x, wp1.w, fmaf(s.y, wu1.w, b1v.w)), 0.f); a1[r].w = fmaf(s.z, v, a1[r].w);
            }
        }
        if (c + 1 < NCHUNK) {
            int nb = (c + 1) & 1;
            float4* dst = (float4*)bl[nb];
            dst[tid] = pre0; dst[tid + 1024] = pre1;
            if (tid < 256) {
                int rr = tid >> 6, jj = tid & 63;
                sc[nb][rr][jj] = make_float4(ppd, put, al[rr][(c + 1) * MJC + jj], 0.f);
            }
        }
        __syncthreads();
    }

    // ---- cross-group reduce: 64 groups -> 32 slots -> tl (racc overlays bl) ----
    if (g < 32) {
        #pragma unroll
        for (int r = 0; r < MROWS; r++) {
            *(float4*)&racc[g][r][k0a] = a0[r];
            *(float4*)&racc[g][r][k0b] = a1[r];
        }
    }
    __syncthreads();
    if (g >= 32) {
        int g2 = g - 32;
        #pragma unroll
        for (int r = 0; r < MROWS; r++) {
            float4 t0 = *(const float4*)&racc[g2][r][k0a];
            float4 t1 = *(const float4*)&racc[g2][r][k0b];
            t0.x += a0[r].x; t0.y += a0[r].y; t0.z += a0[r].z; t0.w += a0[r].w;
            t1.x += a1[r].x; t1.y += a1[r].y; t1.z += a1[r].z; t1.w += a1[r].w;
            *(float4*)&racc[g2][r][k0a] = t0;
            *(float4*)&racc[g2][r][k0b] = t1;
        }
    }
    __syncthreads();
    if (tid < 512) {
        int rr = tid >> 7, k = tid & 127;
        float v = 0.f;
        #pragma unroll
        for (int g2 = 0; g2 < 32; g2++) v += racc[g2][rr][k];
        tl[rr][k] = v;
    }
    __syncthreads();
    // ---- final GEMM: out[i][d] = sum_k t[k] * W2t[k][d] + gate*b2[d] ----
    if (tid < 512) {
        int rr = tid >> 7, d = tid & 127;
        float acc = (gsum[rr] > 0.f) ? b2[d] : 0.f;
        #pragma unroll 8
        for (int k = 0; k < D; k++)
            acc = fmaf(tl[rr][k], W2t[k * D + d], acc);
        out[(i0 + rr) * D + d] = acc;
    }
}

// ---------------------------------------------------------------------------
extern "C" void kernel_launch(void* const* d_in, const int* in_sizes, int n_in,
                              void* d_out, int out_size, void* d_ws, size_t ws_size,
                              hipStream_t stream) {
    (void)in_sizes; (void)n_in; (void)out_size; (void)ws_size;
    const float* h   = (const float*)d_in[0];
    const int*   adj = (const int*)d_in[1];
    const float* pd  = (const float*)d_in[2];
    const float* ut  = (const float*)d_in[3];
    const float* W   = (const float*)d_in[4];
    const float* a   = (const float*)d_in[5];
    const float* W1  = (const float*)d_in[6];
    const float* b1  = (const float*)d_in[7];
    const float* W2  = (const float*)d_in[8];
    const float* b2  = (const float*)d_in[9];
    float* out = (float*)d_out;
    float* ws = (float*)d_ws;

    float* W2t   = ws + OFF_W2T;
    float* wpd   = ws + OFF_WPD;
    float* wut   = ws + OFF_WUT;
    float* s1    = ws + OFF_S1;
    float* s2    = ws + OFF_S2;
    float* baseb = ws + OFF_BASE;

    prep_base_kernel<<<261, 256, 0, stream>>>(W, W1, W2, a, h, b1,
                                              W2t, wpd, wut, s1, s2, baseb);
    mega_kernel<<<N / MROWS, 1024, 0, stream>>>(baseb, s1, s2, adj, pd, ut,
                                                wpd, wut, W2t, b2, out);
}

// Round 9
// 44.066 us; speedup vs baseline: 2.5596x; 1.0553x over previous
//
#include <hip/hip_runtime.h>
#include <hip/hip_bf16.h>

#define N 1024
#define D 128
#define LEAK 0.2f

#define MROWS 4          // i-rows per mega block

// workspace layout (float offsets)
#define OFF_W2T  0
#define OFF_WPD  16384
#define OFF_WUT  16512
#define OFF_S1   16640
#define OFF_S2   17664
#define OFF_BASE 18688

// ---------------------------------------------------------------------------
// K_A: prep + base fused (byte-identical to round 8).
//   b 0..255 : rows 4b..4b+3:  Wh = h@W^T (LDS), s1/s2 = Wh@a, base = Wh@W1h^T + b1
//   b 256..259: W2t 32-row tile (W2t[k][d] = W2[d][k])
//   b 260     : wpd/wut extraction
__global__ __launch_bounds__(256) void prep_base_kernel(
    const float* __restrict__ W, const float* __restrict__ W1,
    const float* __restrict__ W2, const float* __restrict__ a,
    const float* __restrict__ h, const float* __restrict__ b1,
    float* __restrict__ W2t, float* __restrict__ wpd, float* __restrict__ wut,
    float* __restrict__ s1, float* __restrict__ s2, float* __restrict__ base) {
    __shared__ float pool[4160];
    int b = blockIdx.x, tid = threadIdx.x;
    if (b < 256) {
        float* hl  = pool;          // [4][128]
        float* whl = pool + 512;    // [4][128]
        int i0 = b * 4;
        if (tid < 128) ((float4*)hl)[tid] = ((const float4*)(h + i0 * D))[tid];
        __syncthreads();
        int r = tid >> 6, l = tid & 63;
        int k0 = l * 2;
        float u0 = 0.f, u1 = 0.f;
        #pragma unroll 8
        for (int q = 0; q < D; q += 4) {
            float4 hq = *(const float4*)&hl[r * D + q];
            float4 w0 = *(const float4*)&W[k0 * D + q];
            float4 w1 = *(const float4*)&W[(k0 + 1) * D + q];
            u0 = fmaf(hq.x, w0.x, u0); u0 = fmaf(hq.y, w0.y, u0);
            u0 = fmaf(hq.z, w0.z, u0); u0 = fmaf(hq.w, w0.w, u0);
            u1 = fmaf(hq.x, w1.x, u1); u1 = fmaf(hq.y, w1.y, u1);
            u1 = fmaf(hq.z, w1.z, u1); u1 = fmaf(hq.w, w1.w, u1);
        }
        whl[r * D + k0] = u0;
        whl[r * D + k0 + 1] = u1;
        __syncthreads();
        {
            float w0 = whl[r * D + l], w1 = whl[r * D + 64 + l];
            float p1 = fmaf(w0, a[l], w1 * a[64 + l]);
            float p2 = fmaf(w0, a[D + l], w1 * a[D + 64 + l]);
            #pragma unroll
            for (int off = 32; off > 0; off >>= 1) {
                p1 += __shfl_xor(p1, off);
                p2 += __shfl_xor(p2, off);
            }
            if (l == 0) { s1[i0 + r] = p1; s2[i0 + r] = p2; }
        }
        int d0 = l * 2;
        float a0 = b1[d0], a1 = b1[d0 + 1];
        #pragma unroll 8
        for (int q = 0; q < D; q += 2) {
            float2 wh2 = *(const float2*)&whl[r * D + q];
            float2 x0 = *(const float2*)&W1[d0 * (D + 2) + q];
            float2 x1 = *(const float2*)&W1[(d0 + 1) * (D + 2) + q];
            a0 = fmaf(wh2.x, x0.x, a0); a0 = fmaf(wh2.y, x0.y, a0);
            a1 = fmaf(wh2.x, x1.x, a1); a1 = fmaf(wh2.y, x1.y, a1);
        }
        *(float2*)&base[(i0 + r) * D + d0] = make_float2(a0, a1);
    } else if (b < 260) {
        int kbase = 32 * (b - 256);
        #pragma unroll
        for (int p = 0; p < 16; p++) {
            int idx = tid + p * 256;
            int rd = idx >> 5, cc = idx & 31;
            pool[cc * 129 + rd] = W2[rd * D + kbase + cc];
        }
        __syncthreads();
        #pragma unroll
        for (int p = 0; p < 16; p++) {
            int idx = tid + p * 256;
            int kl = idx >> 7, dd = idx & 127;
            W2t[(kbase + kl) * D + dd] = pool[kl * 129 + dd];
        }
    } else {
        if (tid < 128) wpd[tid] = W1[tid * (D + 2) + D];
        else           wut[tid - 128] = W1[(tid - 128) * (D + 2) + D + 1];
    }
}

// ---------------------------------------------------------------------------
// K_B: mega v3 — barrier-free main loop.
//   1024 thr = 64 groups x 16 lanes; group g owns j = c*64+g, c=0..15.
//   Lane l16 owns k-slices [4*l16, 4*l16+4) and [64+4*l16, ...): a group's
//   16 lanes read base[j][...] as two coalesced 256B segments straight from
//   L2 (no LDS staging, no __syncthreads in the loop).
//   Epilogue: shfl butterfly (4 groups/wave) -> racc[16 waves] -> tl -> GEMM.
__global__ __launch_bounds__(1024) void mega_kernel(
    const float* __restrict__ base, const float* __restrict__ s1,
    const float* __restrict__ s2, const int* __restrict__ adj,
    const float* __restrict__ pd, const float* __restrict__ ut,
    const float* __restrict__ wpd, const float* __restrict__ wut,
    const float* __restrict__ W2t, const float* __restrict__ b2,
    float* __restrict__ out) {
    __shared__ float al[MROWS][N];         // 16KB alpha
    __shared__ float racc[16][MROWS][D];   // 32KB wave partials
    __shared__ float red[16], red2[16], gsum[MROWS];
    __shared__ float tl[MROWS][D];

    const int tid = threadIdx.x;           // 0..1023
    const int i0 = blockIdx.x * MROWS;

    // ---- phase 0: alpha (row r <-> 256 threads = waves 4r..4r+3) ----
    {
        int r = tid >> 8;
        int i = i0 + r;
        int jb = (tid & 255) * 4;
        float s1i = s1[i];
        float4 sa = *(const float4*)&s2[jb];
        int4 ma = *(const int4*)&adj[i * N + jb];
        float e[4]; int mm[4];
        e[0] = s1i + sa.x; e[1] = s1i + sa.y; e[2] = s1i + sa.z; e[3] = s1i + sa.w;
        mm[0] = ma.x; mm[1] = ma.y; mm[2] = ma.z; mm[3] = ma.w;
        float mx = -3e38f;
        #pragma unroll
        for (int q = 0; q < 4; q++) {
            e[q] = e[q] > 0.f ? e[q] : LEAK * e[q];
            if (mm[q] > 0) mx = fmaxf(mx, e[q]);
        }
        #pragma unroll
        for (int off = 32; off > 0; off >>= 1) mx = fmaxf(mx, __shfl_xor(mx, off));
        int wid = tid >> 6, lane = tid & 63;
        if (lane == 0) red[wid] = mx;
        __syncthreads();
        mx = fmaxf(fmaxf(red[4 * r], red[4 * r + 1]),
                   fmaxf(red[4 * r + 2], red[4 * r + 3]));
        float ev[4]; float sum = 0.f;
        #pragma unroll
        for (int q = 0; q < 4; q++) {
            ev[q] = (mm[q] > 0) ? __expf(e[q] - mx) : 0.f;
            sum += ev[q];
        }
        #pragma unroll
        for (int off = 32; off > 0; off >>= 1) sum += __shfl_xor(sum, off);
        if (lane == 0) red2[wid] = sum;
        __syncthreads();
        sum = red2[4 * r] + red2[4 * r + 1] + red2[4 * r + 2] + red2[4 * r + 3];
        float inv = sum > 0.f ? 1.f / sum : 0.f;
        *(float4*)&al[r][jb] = make_float4(ev[0] * inv, ev[1] * inv, ev[2] * inv, ev[3] * inv);
        if ((tid & 255) == 0) gsum[r] = sum;
    }
    __syncthreads();   // al + gsum visible; no further barriers until epilogue

    const int l16 = tid & 15, g = tid >> 4;        // 64 groups x 16 lanes
    const int k0a = l16 * 4, k0b = 64 + l16 * 4;
    const float4 wp0 = *(const float4*)&wpd[k0a];
    const float4 wp1 = *(const float4*)&wpd[k0b];
    const float4 wu0 = *(const float4*)&wut[k0a];
    const float4 wu1 = *(const float4*)&wut[k0b];

    const float* pdb = pd + (size_t)i0 * N;
    const float* utb = ut + (size_t)i0 * N;

    float4 a0[MROWS] = {}, a1[MROWS] = {};

    #pragma unroll 2
    for (int c = 0; c < 16; c++) {
        int j = c * 64 + g;
        float4 b0  = *(const float4*)&base[j * D + k0a];
        float4 b1v = *(const float4*)&base[j * D + k0b];
        #pragma unroll
        for (int r = 0; r < MROWS; r++) {
            float spd = pdb[r * N + j];
            float sut = utb[r * N + j];
            float sal = al[r][j];
            float v;
            v = fmaxf(fmaf(spd, wp0.x, fmaf(sut, wu0.x, b0.x)), 0.f);  a0[r].x = fmaf(sal, v, a0[r].x);
            v = fmaxf(fmaf(spd, wp0.y, fmaf(sut, wu0.y, b0.y)), 0.f);  a0[r].y = fmaf(sal, v, a0[r].y);
            v = fmaxf(fmaf(spd, wp0.z, fmaf(sut, wu0.z, b0.z)), 0.f);  a0[r].z = fmaf(sal, v, a0[r].z);
            v = fmaxf(fmaf(spd, wp0.w, fmaf(sut, wu0.w, b0.w)), 0.f);  a0[r].w = fmaf(sal, v, a0[r].w);
            v = fmaxf(fmaf(spd, wp1.x, fmaf(sut, wu1.x, b1v.x)), 0.f); a1[r].x = fmaf(sal, v, a1[r].x);
            v = fmaxf(fmaf(spd, wp1.y, fmaf(sut, wu1.y, b1v.y)), 0.f); a1[r].y = fmaf(sal, v, a1[r].y);
            v = fmaxf(fmaf(spd, wp1.z, fmaf(sut, wu1.z, b1v.z)), 0.f); a1[r].z = fmaf(sal, v, a1[r].z);
            v = fmaxf(fmaf(spd, wp1.w, fmaf(sut, wu1.w, b1v.w)), 0.f); a1[r].w = fmaf(sal, v, a1[r].w);
        }
    }

    // ---- in-wave cross-group reduce: lanes l, l^16, l^32, l^48 share l16 ----
    #pragma unroll
    for (int r = 0; r < MROWS; r++) {
        #pragma unroll
        for (int m = 16; m <= 32; m <<= 1) {
            a0[r].x += __shfl_xor(a0[r].x, m); a0[r].y += __shfl_xor(a0[r].y, m);
            a0[r].z += __shfl_xor(a0[r].z, m); a0[r].w += __shfl_xor(a0[r].w, m);
            a1[r].x += __shfl_xor(a1[r].x, m); a1[r].y += __shfl_xor(a1[r].y, m);
            a1[r].z += __shfl_xor(a1[r].z, m); a1[r].w += __shfl_xor(a1[r].w, m);
        }
    }
    {
        int w = tid >> 6, lane = tid & 63;
        if (lane < 16) {
            #pragma unroll
            for (int r = 0; r < MROWS; r++) {
                *(float4*)&racc[w][r][k0a] = a0[r];
                *(float4*)&racc[w][r][k0b] = a1[r];
            }
        }
    }
    __syncthreads();
    if (tid < 512) {
        int rr = tid >> 7, k = tid & 127;
        float v = 0.f;
        #pragma unroll
        for (int w = 0; w < 16; w++) v += racc[w][rr][k];
        tl[rr][k] = v;
    }
    __syncthreads();
    // ---- final GEMM: out[i][d] = sum_k t[k] * W2t[k][d] + gate*b2[d] ----
    if (tid < 512) {
        int rr = tid >> 7, d = tid & 127;
        float acc = (gsum[rr] > 0.f) ? b2[d] : 0.f;
        #pragma unroll 8
        for (int k = 0; k < D; k++)
            acc = fmaf(tl[rr][k], W2t[k * D + d], acc);
        out[(i0 + rr) * D + d] = acc;
    }
}

// ---------------------------------------------------------------------------
extern "C" void kernel_launch(void* const* d_in, const int* in_sizes, int n_in,
                              void* d_out, int out_size, void* d_ws, size_t ws_size,
                              hipStream_t stream) {
    (void)in_sizes; (void)n_in; (void)out_size; (void)ws_size;
    const float* h   = (const float*)d_in[0];
    const int*   adj = (const int*)d_in[1];
    const float* pd  = (const float*)d_in[2];
    const float* ut  = (const float*)d_in[3];
    const float* W   = (const float*)d_in[4];
    const float* a   = (const float*)d_in[5];
    const float* W1  = (const float*)d_in[6];
    const float* b1  = (const float*)d_in[7];
    const float* W2  = (const float*)d_in[8];
    const float* b2  = (const float*)d_in[9];
    float* out = (float*)d_out;
    float* ws = (float*)d_ws;

    float* W2t   = ws + OFF_W2T;
    float* wpd   = ws + OFF_WPD;
    float* wut   = ws + OFF_WUT;
    float* s1    = ws + OFF_S1;
    float* s2    = ws + OFF_S2;
    float* baseb = ws + OFF_BASE;

    prep_base_kernel<<<261, 256, 0, stream>>>(W, W1, W2, a, h, b1,
                                              W2t, wpd, wut, s1, s2, baseb);
    mega_kernel<<<N / MROWS, 1024, 0, stream>>>(baseb, s1, s2, adj, pd, ut,
                                                wpd, wut, W2t, b2, out);
}